// Round 10
// baseline (3248.396 us; speedup 1.0000x reference)
//
#include <hip/hip_runtime.h>
#include <hip/hip_bf16.h>
#include <stdint.h>

#define BATCH 32
#define SEQT  512
#define DIM   256
#define UU    512
#define SENT  0x7FC07FC0u   // bf16 NaN pair: finite h/x data can never equal this

typedef __attribute__((ext_vector_type(8))) short bf16x8;
typedef __attribute__((ext_vector_type(4))) float f32x4;
typedef __attribute__((ext_vector_type(4))) unsigned int u32x4;

__device__ __forceinline__ short f2bf(float f) {
  uint32_t u = __builtin_bit_cast(uint32_t, f);
  u += 0x7FFFu + ((u >> 16) & 1u);   // RNE; finite in -> finite out (never NaN)
  return (short)(u >> 16);
}
__device__ __forceinline__ uint32_t pack2(float a, float b) {
  return ((uint32_t)(uint16_t)f2bf(b) << 16) | (uint16_t)f2bf(a);
}
__device__ __forceinline__ float sigm(float x) { return 1.0f / (1.0f + __expf(-x)); }
__device__ __forceinline__ float tanh_fast(float x) {
  float ax = fabsf(x);
  float t = __expf(-2.0f * ax);
  float r = (1.0f - t) / (1.0f + t);
  return copysignf(r, x);
}

// write-through stores (visible at LLC); fire-and-forget
__device__ __forceinline__ void st4_wt(void* p, uint32_t v) {
  asm volatile("global_store_dword %0, %1, off sc0 sc1" :: "v"(p), "v"(v) : "memory");
}
__device__ __forceinline__ void st16_wt(void* p, u32x4 v) {
  asm volatile("global_store_dwordx4 %0, %1, off sc0 sc1" :: "v"(p), "v"(v) : "memory");
}

// ONE asm block: 16x 16B LLC-coherent loads off a single base + imm offsets,
// waitcnt INSIDE the block (no asm output live across a wait). Syntax validated r9.
__device__ __forceinline__ void poll_load16(bf16x8 (&d)[16], const short* p) {
  asm volatile(
    "global_load_dwordx4 %0, %16, off sc0 sc1\n\t"
    "global_load_dwordx4 %1, %16, off offset:64 sc0 sc1\n\t"
    "global_load_dwordx4 %2, %16, off offset:128 sc0 sc1\n\t"
    "global_load_dwordx4 %3, %16, off offset:192 sc0 sc1\n\t"
    "global_load_dwordx4 %4, %16, off offset:256 sc0 sc1\n\t"
    "global_load_dwordx4 %5, %16, off offset:320 sc0 sc1\n\t"
    "global_load_dwordx4 %6, %16, off offset:384 sc0 sc1\n\t"
    "global_load_dwordx4 %7, %16, off offset:448 sc0 sc1\n\t"
    "global_load_dwordx4 %8, %16, off offset:512 sc0 sc1\n\t"
    "global_load_dwordx4 %9, %16, off offset:576 sc0 sc1\n\t"
    "global_load_dwordx4 %10, %16, off offset:640 sc0 sc1\n\t"
    "global_load_dwordx4 %11, %16, off offset:704 sc0 sc1\n\t"
    "global_load_dwordx4 %12, %16, off offset:768 sc0 sc1\n\t"
    "global_load_dwordx4 %13, %16, off offset:832 sc0 sc1\n\t"
    "global_load_dwordx4 %14, %16, off offset:896 sc0 sc1\n\t"
    "global_load_dwordx4 %15, %16, off offset:960 sc0 sc1\n\t"
    "s_waitcnt vmcnt(0)"
    : "=&v"(d[0]), "=&v"(d[1]), "=&v"(d[2]), "=&v"(d[3]),
      "=&v"(d[4]), "=&v"(d[5]), "=&v"(d[6]), "=&v"(d[7]),
      "=&v"(d[8]), "=&v"(d[9]), "=&v"(d[10]), "=&v"(d[11]),
      "=&v"(d[12]), "=&v"(d[13]), "=&v"(d[14]), "=&v"(d[15])
    : "v"(p)
    : "memory");
}

__device__ __forceinline__ int valid16(const bf16x8 (&a)[16]) {
  uint32_t ok = 1;
#pragma unroll
  for (int i = 0; i < 16; ++i) {
    u32x4 q = __builtin_bit_cast(u32x4, a[i]);
    ok &= (q[0] != SENT) & (q[1] != SENT) & (q[2] != SENT) & (q[3] != SENT);
  }
  return (int)ok;
}

// poll one 16-row x 512-col bf16 tile into padded LDS; one wave (64 lanes) covers it
#define LDP 520   // padded row length in shorts (+8 -> +16B: spreads LDS banks)
__device__ __forceinline__ void poll_tile(short (*dst)[LDP], const short* src,
                                          int arow, int kq, int& budget) {
  bf16x8 d[16];
  const short* p = src + (size_t)arow * UU + kq * 8;
  while (true) {
    poll_load16(d, p);
    if (__all(valid16(d))) break;
    if (--budget < 0) break;
  }
#pragma unroll
  for (int ks = 0; ks < 16; ++ks)
    *(bf16x8*)&dst[arow][kq * 8 + ks * 32] = d[ks];
}

// sentinel-fill the H buffers
__global__ void fill_sent(uint32_t* __restrict__ p, size_t n16) {
  u32x4 s = {SENT, SENT, SENT, SENT};
  for (size_t i = blockIdx.x * blockDim.x + threadIdx.x; i < n16;
       i += (size_t)gridDim.x * blockDim.x)
    st16_wt(p + i * 4, s);
}

// One layer's persistent scan. 64 WGs/layer = 32 unit-blocks x 2 row-groups;
// WG owns 16 units x 16 rows; wave = gate for MFMA. Wave-specialized sync:
// wave0 polls x-tile, wave1 polls h-tile (concurrent), waves 2,3 do the
// epilogue + fire-and-forget 4B h-stores (concurrent with the polls).
template<int XSTEPS, bool XF32>
__device__ void scan_body(
    int jblk, int rbase,
    const float* __restrict__ xf,       // [B][T][D] (layer 0 only)
    const short* __restrict__ Hprev,    // prev layer H [T+1][32][512]
    short*       __restrict__ Hown,     // own H [T+1][32][512]
    const float* __restrict__ W,        // [KX][2048]
    const float* __restrict__ R,        // [512][2048]
    const float* __restrict__ bias,     // [2048]
    const float* __restrict__ hinit,    // [512]
    const float* __restrict__ cinit)    // [512]
{
  const int tid  = threadIdx.x;
  const int g    = tid >> 6;            // wave = gate (i,f,g,o)
  const int lane = tid & 63;
  const int arow = lane & 15;
  const int kq   = lane >> 4;
  const int jbase = jblk * 16;
  const int colg  = g * UU + jbase + arow;

  // ---- one-time: weight B-fragments into registers ----
  bf16x8 bw[XSTEPS];
  bf16x8 br[16];
#pragma unroll
  for (int ks = 0; ks < XSTEPS; ++ks) {
    bf16x8 v;
#pragma unroll
    for (int jj = 0; jj < 8; ++jj)
      v[jj] = f2bf(W[(size_t)(ks * 32 + kq * 8 + jj) * 2048 + colg]);
    bw[ks] = v;
  }
#pragma unroll
  for (int ks = 0; ks < 16; ++ks) {
    bf16x8 v;
#pragma unroll
    for (int jj = 0; jj < 8; ++jj)
      v[jj] = f2bf(R[(size_t)(ks * 32 + kq * 8 + jj) * 2048 + colg]);
    br[ks] = v;
  }

  // ---- epilogue mapping (used by waves 2,3): thread -> (row8, unit pair) ----
  const int et   = tid & 127;
  const int row8 = et >> 3;             // 0..15
  const int pair = et & 7;
  const int u0 = 2 * pair, u1 = u0 + 1;
  float biasv[4][2];
#pragma unroll
  for (int gg = 0; gg < 4; ++gg) {
    biasv[gg][0] = bias[gg * UU + jbase + u0];
    biasv[gg][1] = bias[gg * UU + jbase + u1];
  }
  float cr0 = cinit[jbase + u0];
  float cr1 = cinit[jbase + u1];

  __shared__ float zsm[4][16][16];
  __shared__ short xtile[16][LDP];      // x tile for this step (layers 1,2)
  __shared__ short htile[16][LDP];      // h tile for this step

  int budget = 1 << 18;                 // termination valve (never hang)

  // ---- prologue: init-tile stores (waves 2,3) + polls for step 0 ----
  if (tid >= 128) {
    uint32_t pk = pack2(hinit[jbase + u0], hinit[jbase + u1]);
    st4_wt(Hown + (size_t)(rbase + row8) * UU + jbase + u0, pk);
  } else if (g == 1) {
    poll_tile(htile, Hown + (size_t)0 * BATCH * UU + (size_t)rbase * UU,
              arow, kq, budget);
  } else if (g == 0 && !XF32) {
    poll_tile(xtile, Hprev + (size_t)1 * BATCH * UU + (size_t)rbase * UU,
              arow, kq, budget);
  }
  __syncthreads();   // B_A: tiles ready

#pragma unroll 1
  for (int t = 0; t < SEQT; ++t) {
    f32x4 acc = {0.f, 0.f, 0.f, 0.f};

    // ---- x @ W ----
    if constexpr (XF32) {
      const float* p = xf + ((size_t)(rbase + arow) * SEQT + t) * DIM + kq * 8;
#pragma unroll
      for (int ks = 0; ks < XSTEPS; ++ks) {
        float4 x0 = *(const float4*)(p + ks * 32);
        float4 x1 = *(const float4*)(p + ks * 32 + 4);
        bf16x8 a;
        a[0] = f2bf(x0.x); a[1] = f2bf(x0.y); a[2] = f2bf(x0.z); a[3] = f2bf(x0.w);
        a[4] = f2bf(x1.x); a[5] = f2bf(x1.y); a[6] = f2bf(x1.z); a[7] = f2bf(x1.w);
        acc = __builtin_amdgcn_mfma_f32_16x16x32_bf16(a, bw[ks], acc, 0, 0, 0);
      }
    } else {
#pragma unroll
      for (int ks = 0; ks < 16; ++ks) {
        bf16x8 a = *(const bf16x8*)&xtile[arow][kq * 8 + ks * 32];
        acc = __builtin_amdgcn_mfma_f32_16x16x32_bf16(a, bw[ks], acc, 0, 0, 0);
      }
    }

    // ---- h @ R from LDS ----
#pragma unroll
    for (int ks = 0; ks < 16; ++ks) {
      bf16x8 a = *(const bf16x8*)&htile[arow][kq * 8 + ks * 32];
      acc = __builtin_amdgcn_mfma_f32_16x16x32_bf16(a, br[ks], acc, 0, 0, 0);
    }

    // ---- exchange z across waves ----
#pragma unroll
    for (int r = 0; r < 4; ++r)
      zsm[g][kq * 4 + r][arow] = acc[r];
    __syncthreads();   // B_zsm

    // ---- waves 2,3: gates + state + fire-and-forget stores;
    //      waves 0,1: concurrently poll next step's tiles ----
    if (tid >= 128) {
      float zi0 = zsm[0][row8][u0] + biasv[0][0];
      float zf0 = zsm[1][row8][u0] + biasv[1][0];
      float zg0 = zsm[2][row8][u0] + biasv[2][0];
      float zo0 = zsm[3][row8][u0] + biasv[3][0];
      float zi1 = zsm[0][row8][u1] + biasv[0][1];
      float zf1 = zsm[1][row8][u1] + biasv[1][1];
      float zg1 = zsm[2][row8][u1] + biasv[2][1];
      float zo1 = zsm[3][row8][u1] + biasv[3][1];
      cr0 = sigm(zf0) * cr0 + sigm(zi0) * tanh_fast(zg0);
      cr1 = sigm(zf1) * cr1 + sigm(zi1) * tanh_fast(zg1);
      uint32_t pk = pack2(sigm(zo0) * tanh_fast(cr0),
                          sigm(zo1) * tanh_fast(cr1));
      st4_wt(Hown + ((size_t)(t + 1) * BATCH + rbase + row8) * UU + jbase + u0, pk);
    } else if (t + 1 < SEQT) {
      if (g == 1) {
        poll_tile(htile, Hown + (size_t)(t + 1) * BATCH * UU + (size_t)rbase * UU,
                  arow, kq, budget);
      } else if (!XF32) {
        poll_tile(xtile, Hprev + (size_t)(t + 2) * BATCH * UU + (size_t)rbase * UU,
                  arow, kq, budget);
      }
    }
    __syncthreads();   // B_A: next tiles ready, zsm free
  }
}

__global__ __launch_bounds__(256, 1) void lstm_scan(
    const float* __restrict__ inputs,
    const float* __restrict__ W0, const float* __restrict__ R0, const float* __restrict__ b0,
    const float* __restrict__ h0i, const float* __restrict__ c0i,
    const float* __restrict__ W1, const float* __restrict__ R1, const float* __restrict__ b1,
    const float* __restrict__ h1i, const float* __restrict__ c1i,
    const float* __restrict__ W2, const float* __restrict__ R2, const float* __restrict__ b2,
    const float* __restrict__ h2i, const float* __restrict__ c2i,
    short* __restrict__ H0, short* __restrict__ H1, short* __restrict__ H2)
{
  const int layer = blockIdx.x >> 6;    // 0..2
  const int sub   = blockIdx.x & 63;
  const int jblk  = sub & 31;
  const int rbase = (sub >> 5) * 16;

  if (layer == 0)
    scan_body<8,  true >(jblk, rbase, inputs, nullptr, H0, W0, R0, b0, h0i, c0i);
  else if (layer == 1)
    scan_body<16, false>(jblk, rbase, nullptr, H0, H1, W1, R1, b1, h1i, c1i);
  else
    scan_body<16, false>(jblk, rbase, nullptr, H1, H2, W2, R2, b2, h2i, c2i);
}

// Y[b][t][:] = H2[t+1][b][:] @ Wd + bd.  Tile: 128 rows x 64 cols per WG.
__global__ __launch_bounds__(256, 2) void dense_out(
    const short* __restrict__ H2,      // [T+1][32][512]
    const float* __restrict__ Wd,      // [512][256]
    const float* __restrict__ bd,      // [256]
    float* __restrict__ out)           // [32][512][256]
{
  const int mblock = blockIdx.x;       // 0..127
  const int nblock = blockIdx.y;       // 0..3
  const int tid  = threadIdx.x;
  const int wave = tid >> 6;
  const int lane = tid & 63;
  const int col  = lane & 15;
  const int kq   = lane >> 4;

  __shared__ short wlds[64][264];

  f32x4 acc[2][4];
#pragma unroll
  for (int mi = 0; mi < 2; ++mi)
#pragma unroll
    for (int ni = 0; ni < 4; ++ni)
      acc[mi][ni] = f32x4{0.f, 0.f, 0.f, 0.f};

  const short* Abase = H2 + (size_t)32 * UU;   // skip init tile

  for (int half = 0; half < 2; ++half) {
    __syncthreads();
    for (int idx = tid; idx < 256 * 64; idx += 256) {
      int k = idx >> 6;
      int c = idx & 63;
      wlds[c][k] = f2bf(Wd[(size_t)(half * 256 + k) * 256 + nblock * 64 + c]);
    }
    __syncthreads();
#pragma unroll
    for (int ks = 0; ks < 8; ++ks) {
      const int d0g = half * 256 + ks * 32 + kq * 8;
      const int d0l = ks * 32 + kq * 8;
      const size_t r0 = (size_t)(mblock * 128 + wave * 32 + col) * UU;
      const size_t r1 = (size_t)(mblock * 128 + wave * 32 + 16 + col) * UU;
      bf16x8 a0 = *(const bf16x8*)(Abase + r0 + d0g);
      bf16x8 a1 = *(const bf16x8*)(Abase + r1 + d0g);
#pragma unroll
      for (int ni = 0; ni < 4; ++ni) {
        bf16x8 bv = *(const bf16x8*)(&wlds[ni * 16 + col][d0l]);
        acc[0][ni] = __builtin_amdgcn_mfma_f32_16x16x32_bf16(a0, bv, acc[0][ni], 0, 0, 0);
        acc[1][ni] = __builtin_amdgcn_mfma_f32_16x16x32_bf16(a1, bv, acc[1][ni], 0, 0, 0);
      }
    }
  }

#pragma unroll
  for (int ni = 0; ni < 4; ++ni) {
    float bdv = bd[nblock * 64 + ni * 16 + col];
#pragma unroll
    for (int mi = 0; mi < 2; ++mi) {
#pragma unroll
      for (int r = 0; r < 4; ++r) {
        int grow = mblock * 128 + wave * 32 + mi * 16 + kq * 4 + r;
        int t = grow >> 5, b = grow & 31;
        out[((size_t)b * SEQT + t) * DIM + nblock * 64 + ni * 16 + col] = acc[mi][ni][r] + bdv;
      }
    }
  }
}

extern "C" void kernel_launch(void* const* d_in, const int* in_sizes, int n_in,
                              void* d_out, int out_size, void* d_ws, size_t ws_size,
                              hipStream_t stream) {
  const float* inputs = (const float*)d_in[0];
  const float* W0 = (const float*)d_in[1];
  const float* R0 = (const float*)d_in[2];
  const float* b0 = (const float*)d_in[3];
  const float* h0 = (const float*)d_in[4];
  const float* c0 = (const float*)d_in[5];
  const float* W1 = (const float*)d_in[6];
  const float* R1 = (const float*)d_in[7];
  const float* b1 = (const float*)d_in[8];
  const float* h1 = (const float*)d_in[9];
  const float* c1 = (const float*)d_in[10];
  const float* W2 = (const float*)d_in[11];
  const float* R2 = (const float*)d_in[12];
  const float* b2 = (const float*)d_in[13];
  const float* h2 = (const float*)d_in[14];
  const float* c2 = (const float*)d_in[15];
  const float* Wd = (const float*)d_in[16];
  const float* bd = (const float*)d_in[17];

  char* base = (char*)d_ws;
  const size_t HX = (size_t)(SEQT + 1) * BATCH * UU * sizeof(short); // ~16.8 MB
  short* H0 = (short*)(base);
  short* H1 = (short*)(base + HX);
  short* H2 = (short*)(base + 2 * HX);

  // re-arm sentinels every launch (replay-safe)
  const size_t n16 = 3 * HX / 16;
  hipLaunchKernelGGL(fill_sent, dim3(2048), dim3(256), 0, stream,
                     (uint32_t*)base, n16);

  hipLaunchKernelGGL(lstm_scan, dim3(192), dim3(256), 0, stream,
                     inputs, W0, R0, b0, h0, c0, W1, R1, b1, h1, c1,
                     W2, R2, b2, h2, c2, H0, H1, H2);

  hipLaunchKernelGGL(dense_out, dim3(128, 4), dim3(256), 0, stream,
                     H2, Wd, bd, (float*)d_out);
}